// Round 9
// baseline (104.935 us; speedup 1.0000x reference)
//
#include <hip/hip_runtime.h>
#include <hip/hip_bf16.h>
#include <math.h>
#include <stdint.h>

#define EPS 1e-5f

typedef __attribute__((ext_vector_type(8))) short bf16x8;
typedef __attribute__((ext_vector_type(16))) float f32x16;

__device__ __forceinline__ ushort f2bf(float f) {
    union { float f; unsigned u; } v; v.f = f;
    unsigned r = (v.u + 0x7FFFu + ((v.u >> 16) & 1u)) >> 16;
    return (ushort)r;
}

__device__ __forceinline__ void dma16(const void* g, void* l) {
    __builtin_amdgcn_global_load_lds(
        (__attribute__((address_space(1))) const void*)(uintptr_t)g,
        (__attribute__((address_space(3))) void*)(uintptr_t)l,
        16, 0, 0);
}

// ---------------------------------------------------------------------------
// Kernel 1: transpose x -> xTq[b][q 4][y 66][c 66][ic 32] bf16 (borders zero),
// QUARTER-MAJOR so conv's quarter stages read dense 64B runs.
// Also accumulates pooled via atomics.  grid = 2048, XCD-grouped by sample.
// ---------------------------------------------------------------------------
__global__ __launch_bounds__(256) void transpose_kernel(const float* __restrict__ x,
                                                        ushort* __restrict__ xTq,
                                                        float* __restrict__ pooled) {
    __shared__ float T[128][68];                  // 34816 B; b128-aligned rows
    int bid = blockIdx.x;
    int b = (bid & 7) * 4 + (bid >> 9);
    int y = (bid >> 3) & 63;
    int t = threadIdx.x;

    // phase 1: load x[b][ic][y][:], sum, stash row in LDS (b128 writes)
    int ic2 = t >> 1, half = t & 1;
    const float4* src = (const float4*)(x + (((size_t)b * 128 + ic2) * 64 + y) * 64 + half * 32);
    float4* trow = (float4*)&T[ic2][half * 32];
    float s = 0.f;
#pragma unroll
    for (int i = 0; i < 8; ++i) {
        float4 v = src[i];
        trow[i] = v;
        s += v.x + v.y + v.z + v.w;
    }
    s += __shfl_xor(s, 1, 64);
    if (half == 0) atomicAdd(&pooled[b * 128 + ic2], s * (1.0f / 4096.0f));
    __syncthreads();

    // phase 2: thread (col = t&63, icq = t>>6) -> 64B store per quarter
    int col = t & 63, icq = t >> 6;
    uint pk[16];
#pragma unroll
    for (int jj = 0; jj < 16; ++jj) {
        float f0 = T[icq * 32 + 2 * jj][col];
        float f1 = T[icq * 32 + 2 * jj + 1][col];
        pk[jj] = (uint)f2bf(f0) | ((uint)f2bf(f1) << 16);
    }
    ushort* dst = xTq + ((((size_t)(b * 4 + icq) * 66) + y + 1) * 66 + col + 1) * 32;
    ((uint4*)dst)[0] = make_uint4(pk[0], pk[1], pk[2], pk[3]);
    ((uint4*)dst)[1] = make_uint4(pk[4], pk[5], pk[6], pk[7]);
    ((uint4*)dst)[2] = make_uint4(pk[8], pk[9], pk[10], pk[11]);
    ((uint4*)dst)[3] = make_uint4(pk[12], pk[13], pk[14], pk[15]);

    // borders
    uint4 z = make_uint4(0, 0, 0, 0);
    if (y == 0 || y == 63) {
        int row = (y == 0) ? 0 : 65;
        for (int i = t; i < 1056; i += 256) {              // 4 quarters x 264 uint4
            int qq = i / 264, rr = i - qq * 264;
            *(((uint4*)(xTq + (((size_t)(b * 4 + qq) * 66 + row) * 66) * 32)) + rr) = z;
        }
    }
    if (t < 32) {
        int qq = t >> 3, cc = ((t >> 2) & 1) * 65, part = t & 3;
        *(uint4*)(xTq + ((((size_t)(b * 4 + qq) * 66) + y + 1) * 66 + cc) * 32 + part * 8) = z;
    }
}

// ---------------------------------------------------------------------------
// Kernel 2: fused SE MLP + weight aggregation (r8 structure, unchanged).
// A layout: per (b, tap=h*9+s): 1024 chunks; chunk idx = oc*8+((g+oc)&7),
// content = ic [h*64+g*8, +8) of row oc.
// ---------------------------------------------------------------------------
__global__ __launch_bounds__(256) void aggw_kernel(const float* __restrict__ weight,
                                                   const float* __restrict__ pooled,
                                                   const float* __restrict__ se_w1,
                                                   const float* __restrict__ gn1_s, const float* __restrict__ gn1_b,
                                                   const float* __restrict__ se_w2,
                                                   const float* __restrict__ gn2_s, const float* __restrict__ gn2_b,
                                                   float* __restrict__ att_out,
                                                   ushort* __restrict__ aggw) {
    __shared__ float pl[8][128];
    __shared__ float h1s[8][8];
    __shared__ float att_s[8][4];
    int blk = blockIdx.x;
    int rep = blk / 72;
    int t = threadIdx.x;

#pragma unroll
    for (int u = 0; u < 4; ++u) {
        int pid = u * 256 + t;
        int bl = pid >> 7, ic = pid & 127;
        pl[bl][ic] = pooled[(rep * 8 + bl) * 128 + ic];
    }
    __syncthreads();
    if (t < 64) {
        int bl = t >> 3, jj = t & 7;
        float s1 = 0.f;
        for (int c = 0; c < 128; ++c) s1 += pl[bl][c] * se_w1[jj * 128 + c];
        h1s[bl][jj] = s1;
    }
    __syncthreads();
    if (t < 8) {
        float h1[8];
#pragma unroll
        for (int j = 0; j < 8; ++j) h1[j] = h1s[t][j];
        float m = 0.f;
#pragma unroll
        for (int j = 0; j < 8; ++j) m += h1[j];
        m *= 0.125f;
        float var = 0.f;
#pragma unroll
        for (int j = 0; j < 8; ++j) { float d = h1[j] - m; var += d * d; }
        var *= 0.125f;
        float inv = rsqrtf(var + EPS);
#pragma unroll
        for (int j = 0; j < 8; ++j) {
            float tt = (h1[j] - m) * inv * gn1_s[j] + gn1_b[j];
            float sp = (tt > 20.f) ? tt : log1pf(expf(tt));
            h1[j] = tt * tanhf(sp);
        }
        float h2[4];
#pragma unroll
        for (int k = 0; k < 4; ++k) {
            float s2 = 0.f;
#pragma unroll
            for (int j = 0; j < 8; ++j) s2 += h1[j] * se_w2[k * 8 + j];
            h2[k] = s2;
        }
        float m2 = 0.25f * (h2[0] + h2[1] + h2[2] + h2[3]);
        float v2 = 0.f;
#pragma unroll
        for (int k = 0; k < 4; ++k) { float d = h2[k] - m2; v2 += d * d; }
        v2 *= 0.25f;
        float inv2 = rsqrtf(v2 + EPS);
#pragma unroll
        for (int k = 0; k < 4; ++k) {
            float tt = (h2[k] - m2) * inv2 * gn2_s[k] + gn2_b[k];
            att_s[t][k] = 1.0f / (1.0f + expf(-tt));
        }
    }
    __syncthreads();

    if ((blk % 72) == 0 && t < 32) att_out[rep * 32 + t] = att_s[t >> 2][t & 3];

    int tq = (blk % 72) * 256 + t;                     // 0..18431
    int tap = tq >> 10;
    int within = tq & 1023;
    int oc = within >> 3;
    int p = within & 7;
    int g = (p - oc) & 7;
    int h = tap / 9, s = tap % 9;
    int ic0 = h * 64 + g * 8;

    float wv[4][8];
#pragma unroll
    for (int k = 0; k < 4; ++k)
#pragma unroll
        for (int j = 0; j < 8; ++j)
            wv[k][j] = weight[(((size_t)(k * 128 + oc)) * 128 + ic0 + j) * 9 + s];

#pragma unroll
    for (int bl = 0; bl < 8; ++bl) {
        int b = rep * 8 + bl;
        float a0 = att_s[bl][0], a1 = att_s[bl][1], a2 = att_s[bl][2], a3 = att_s[bl][3];
        uint pk[4];
#pragma unroll
        for (int q = 0; q < 4; ++q) {
            float f0 = a0 * wv[0][2 * q] + a1 * wv[1][2 * q] + a2 * wv[2][2 * q] + a3 * wv[3][2 * q];
            float f1 = a0 * wv[0][2 * q + 1] + a1 * wv[1][2 * q + 1] + a2 * wv[2][2 * q + 1] + a3 * wv[3][2 * q + 1];
            pk[q] = (uint)f2bf(f0) | ((uint)f2bf(f1) << 16);
        }
        *(uint4*)(aggw + (size_t)b * 147456 + (size_t)tq * 8) = make_uint4(pk[0], pk[1], pk[2], pk[3]);
    }
}

// ---------------------------------------------------------------------------
// Kernel 3: implicit-GEMM conv, mfma_f32_32x32x16_bf16, QUARTER PIPELINE.
// grid 256 = 32 b * 8 tiles (8 rows), 1 block/CU; block 512 = 8 waves
// (wm: oc-64 half, wn: row-pair 0..3), wave = 64 oc x 128 px, acc[2][4].
// LDS: 2 x 42240 B quarter buffers (32 ic each), double-buffered.
// Per quarter: issue next stage -> 9 taps {4 ds_read, 8 MFMA}x2 + A-ring ->
// s_waitcnt vmcnt(36) (counted, NOT 0) + s_barrier.  A: 2-tap register ring.
// ---------------------------------------------------------------------------
__global__ __launch_bounds__(512, 2) void conv_kernel(const ushort* __restrict__ xTq,
                                                      const ushort* __restrict__ aggw,
                                                      const float* __restrict__ att,
                                                      const float* __restrict__ bias,
                                                      float* __restrict__ out) {
    __shared__ ushort ldsQ[2][21120];                 // 2 x 42240 B

    int bid = blockIdx.x;
    int xcd = bid & 7;
    int idx = bid >> 3;                                // 0..31
    int b = xcd * 4 + (idx >> 3);                      // 4 samples per XCD
    int tile = idx & 7;
    int y0 = tile * 8;

    int tid = threadIdx.x;
    int l = tid & 63, w = tid >> 6;
    int wm = w >> 2, wn = w & 3;
    int l31 = l & 31, lhi = l >> 5;

    const ushort* Asmp = aggw + (size_t)b * 147456;

    int ocofs[2], rotA[2];
#pragma unroll
    for (int mi = 0; mi < 2; ++mi) {
        int oc = wm * 64 + mi * 32 + l31;
        ocofs[mi] = oc * 64;
        rotA[mi] = (lhi + oc) & 7;
    }

    f32x16 acc[2][4];
#pragma unroll
    for (int mi = 0; mi < 2; ++mi)
#pragma unroll
        for (int nb = 0; nb < 4; ++nb)
#pragma unroll
            for (int q = 0; q < 16; ++q) acc[mi][nb][q] = 0.f;

    bf16x8 aR[3][2][2];                                // [tap%3][ib][mi]

#define LOADA(R, Q, S)                                                                       \
    {                                                                                        \
        const ushort* tb_ = Asmp + (size_t)((((Q) >> 1) * 9 + (S))) * 8192;                  \
        _Pragma("unroll")                                                                    \
        for (int ib_ = 0; ib_ < 2; ++ib_)                                                    \
            _Pragma("unroll")                                                                \
            for (int mi_ = 0; mi_ < 2; ++mi_)                                                \
                aR[R][ib_][mi_] = *(const bf16x8*)(tb_ + ocofs[mi_] +                        \
                    (((rotA[mi_] + 4 * ((Q) & 1) + 2 * ib_) & 7) << 3));                     \
    }

    // stage quarter Q into buffer BUF: 2640 chunks of 16B, dense 64B-run reads
#define STAGE(Q, BUF)                                                                        \
    {                                                                                        \
        const ushort* qb_ = xTq + (((size_t)(b * 4 + (Q)) * 66 + y0)) * 66 * 32;             \
        _Pragma("unroll")                                                                    \
        for (int i_ = 0; i_ < 6; ++i_) {                                                     \
            int k_ = i_ * 512 + tid;                                                         \
            if (k_ < 2640) {                                                                 \
                int rc_ = k_ >> 2;                                                           \
                int p_ = k_ & 3;                                                             \
                int r_ = rc_ / 66;                                                           \
                int c_ = rc_ - r_ * 66;                                                      \
                int g_ = (p_ - c_ - (c_ >> 2)) & 3;                                          \
                dma16(qb_ + ((size_t)rc_) * 32 + (g_ << 3), &ldsQ[BUF][(size_t)k_ * 8]);     \
            }                                                                                \
        }                                                                                    \
    }

    // ---- prologue: stage Q0, A taps 0-1, counted drain ----
    STAGE(0, 0);
    __builtin_amdgcn_sched_barrier(0);
    LOADA(0, 0, 0);
    LOADA(1, 0, 1);
    asm volatile("s_waitcnt vmcnt(8)" ::: "memory");
    __builtin_amdgcn_s_barrier();
    __builtin_amdgcn_sched_barrier(0);

    for (int q = 0; q < 4; ++q) {
        const ushort* buf = ldsQ[q & 1];
        if (q < 3) {
            if ((q & 1) == 0) { STAGE(q + 1, 1); } else { STAGE(q + 1, 0); }
            __builtin_amdgcn_sched_barrier(0);
        }
#pragma unroll
        for (int s = 0; s < 9; ++s) {
            const int kh = s / 3, kw = s - kh * 3;
            // ---- ib = 0 ----
            {
                bf16x8 bb[4];
#pragma unroll
                for (int nb = 0; nb < 4; ++nb) {
                    int c = (nb & 1) * 32 + l31 + kw;
                    int cell = (2 * wn + (nb >> 1) + kh) * 66 + c;
                    int p = (lhi + c + (c >> 2)) & 3;
                    bb[nb] = *(const bf16x8*)&buf[(cell << 5) + (p << 3)];
                }
#pragma unroll
                for (int mi = 0; mi < 2; ++mi)
#pragma unroll
                    for (int nb = 0; nb < 4; ++nb)
                        acc[mi][nb] = __builtin_amdgcn_mfma_f32_32x32x16_bf16(aR[s % 3][0][mi], bb[nb], acc[mi][nb], 0, 0, 0);
            }
            // ---- A prefetch (tap +2, crossing quarters) ----
            if (q < 3 || s < 7) {
                if (s < 7) { LOADA((s + 2) % 3, q, s + 2); }
                else if (s == 7) { LOADA(0, q + 1, 0); }
                else { LOADA(1, q + 1, 1); }
            }
            // ---- ib = 1 ----
            {
                bf16x8 bb[4];
#pragma unroll
                for (int nb = 0; nb < 4; ++nb) {
                    int c = (nb & 1) * 32 + l31 + kw;
                    int cell = (2 * wn + (nb >> 1) + kh) * 66 + c;
                    int p = (2 + lhi + c + (c >> 2)) & 3;
                    bb[nb] = *(const bf16x8*)&buf[(cell << 5) + (p << 3)];
                }
#pragma unroll
                for (int mi = 0; mi < 2; ++mi)
#pragma unroll
                    for (int nb = 0; nb < 4; ++nb)
                        acc[mi][nb] = __builtin_amdgcn_mfma_f32_32x32x16_bf16(aR[s % 3][1][mi], bb[nb], acc[mi][nb], 0, 0, 0);
            }
        }
        if (q < 3) {
            // counted: 36 A-loads were issued after this quarter's STAGE ->
            // vmcnt(36) guarantees all staging dma retired; loads stay in flight.
            asm volatile("s_waitcnt vmcnt(36)" ::: "memory");
            __builtin_amdgcn_s_barrier();
            __builtin_amdgcn_sched_barrier(0);
        }
    }

    // ---- epilogue: + att@bias, store ----
    float a0 = att[b * 4 + 0], a1 = att[b * 4 + 1], a2 = att[b * 4 + 2], a3 = att[b * 4 + 3];
#pragma unroll
    for (int mi = 0; mi < 2; ++mi)
#pragma unroll
        for (int q = 0; q < 16; ++q) {
            int oc = wm * 64 + mi * 32 + (q & 3) + 8 * (q >> 2) + 4 * lhi;
            float ab = a0 * bias[oc] + a1 * bias[128 + oc] + a2 * bias[256 + oc] + a3 * bias[384 + oc];
#pragma unroll
            for (int nb = 0; nb < 4; ++nb) {
                int y = y0 + 2 * wn + (nb >> 1);
                out[(((size_t)b * 128 + oc) * 64 + y) * 64 + (nb & 1) * 32 + l31] = acc[mi][nb][q] + ab;
            }
        }
#undef LOADA
#undef STAGE
}

// ---------------------------------------------------------------------------
extern "C" void kernel_launch(void* const* d_in, const int* in_sizes, int n_in,
                              void* d_out, int out_size, void* d_ws, size_t ws_size,
                              hipStream_t stream) {
    const float* x      = (const float*)d_in[0];
    const float* weight = (const float*)d_in[1];
    const float* bias   = (const float*)d_in[2];
    const float* se_w1  = (const float*)d_in[3];
    const float* gn1_s  = (const float*)d_in[4];
    const float* gn1_b  = (const float*)d_in[5];
    const float* se_w2  = (const float*)d_in[6];
    const float* gn2_s  = (const float*)d_in[7];
    const float* gn2_b  = (const float*)d_in[8];
    float* out = (float*)d_out;

    float*  att    = (float*)d_ws;                              // 512 B
    float*  pooled = (float*)((char*)d_ws + 16384);             // 16 KB
    ushort* aggw   = (ushort*)((char*)d_ws + 65536);            // 9.44 MB
    ushort* xTq    = (ushort*)((char*)d_ws + 10485760);         // 35.7 MB (quarter-major)

    hipMemsetAsync(pooled, 0, 128 * 32 * sizeof(float), stream);
    transpose_kernel<<<2048, 256, 0, stream>>>(x, xTq, pooled);
    aggw_kernel<<<288, 256, 0, stream>>>(weight, pooled, se_w1, gn1_s, gn1_b,
                                         se_w2, gn2_s, gn2_b, att, aggw);
    conv_kernel<<<256, 512, 0, stream>>>(xTq, aggw, att, bias, out);
}

// Round 10
// 98.354 us; speedup vs baseline: 1.0669x; 1.0669x over previous
//
#include <hip/hip_runtime.h>
#include <hip/hip_bf16.h>
#include <math.h>
#include <stdint.h>

#define EPS 1e-5f

typedef __attribute__((ext_vector_type(8))) short bf16x8;
typedef __attribute__((ext_vector_type(16))) float f32x16;

__device__ __forceinline__ ushort f2bf(float f) {
    union { float f; unsigned u; } v; v.f = f;
    unsigned r = (v.u + 0x7FFFu + ((v.u >> 16) & 1u)) >> 16;
    return (ushort)r;
}

__device__ __forceinline__ void dma16(const void* g, void* l) {
    __builtin_amdgcn_global_load_lds(
        (__attribute__((address_space(1))) const void*)(uintptr_t)g,
        (__attribute__((address_space(3))) void*)(uintptr_t)l,
        16, 0, 0);
}

// ---------------------------------------------------------------------------
// Kernel 1: transpose x -> xT[b][y 66][c 66][ic 128] bf16 (borders zero),
// plus pooled accumulation via atomics.  grid = 2048, XCD-grouped by sample.
// ---------------------------------------------------------------------------
__global__ __launch_bounds__(256) void transpose_kernel(const float* __restrict__ x,
                                                        ushort* __restrict__ xT,
                                                        float* __restrict__ pooled) {
    __shared__ float T[128][68];
    int bid = blockIdx.x;
    int b = (bid & 7) * 4 + (bid >> 9);
    int y = (bid >> 3) & 63;
    int t = threadIdx.x;

    // phase 1: load x[b][ic][y][:], sum, stash row in LDS (b128 writes)
    int ic2 = t >> 1, half = t & 1;
    const float4* src = (const float4*)(x + (((size_t)b * 128 + ic2) * 64 + y) * 64 + half * 32);
    float4* trow = (float4*)&T[ic2][half * 32];
    float s = 0.f;
#pragma unroll
    for (int i = 0; i < 8; ++i) {
        float4 v = src[i];
        trow[i] = v;
        s += v.x + v.y + v.z + v.w;
    }
    s += __shfl_xor(s, 1, 64);
    if (half == 0) atomicAdd(&pooled[b * 128 + ic2], s * (1.0f / 4096.0f));
    __syncthreads();

    // phase 2: col = t&63, icq = t>>6 -> 64B store per thread
    int col = t & 63, icq = t >> 6;
    uint pk[16];
#pragma unroll
    for (int jj = 0; jj < 16; ++jj) {
        float f0 = T[icq * 32 + 2 * jj][col];
        float f1 = T[icq * 32 + 2 * jj + 1][col];
        pk[jj] = (uint)f2bf(f0) | ((uint)f2bf(f1) << 16);
    }
    ushort* dst = xT + (((size_t)(b * 66 + y + 1)) * 66 + col + 1) * 128 + icq * 32;
    ((uint4*)dst)[0] = make_uint4(pk[0], pk[1], pk[2], pk[3]);
    ((uint4*)dst)[1] = make_uint4(pk[4], pk[5], pk[6], pk[7]);
    ((uint4*)dst)[2] = make_uint4(pk[8], pk[9], pk[10], pk[11]);
    ((uint4*)dst)[3] = make_uint4(pk[12], pk[13], pk[14], pk[15]);

    uint4 z = make_uint4(0, 0, 0, 0);
    if (y == 0) {
        uint4* row0 = (uint4*)(xT + ((size_t)b * 66 + 0) * 66 * 128);
        for (int i = t; i < 1056; i += 256) row0[i] = z;
    }
    if (y == 63) {
        uint4* row65 = (uint4*)(xT + ((size_t)b * 66 + 65) * 66 * 128);
        for (int i = t; i < 1056; i += 256) row65[i] = z;
    }
    if (t < 32) {
        int c = (t >> 4) * 65;
        int i = t & 15;
        *(uint4*)(xT + (((size_t)(b * 66 + y + 1)) * 66 + c) * 128 + i * 8) = z;
    }
}

// ---------------------------------------------------------------------------
// Kernel 2: fused SE MLP + weight aggregation.
// Stored tap order is KW-MAJOR: stored tap s' = kw*3 + kh (weight tap kh*3+kw).
// A layout otherwise unchanged: per (b, tap'): 1024 chunks; chunk idx =
// oc*8+((g+oc)&7), content = ic [h*64+g*8, +8) of row oc.
// ---------------------------------------------------------------------------
__global__ __launch_bounds__(256) void aggw_kernel(const float* __restrict__ weight,
                                                   const float* __restrict__ pooled,
                                                   const float* __restrict__ se_w1,
                                                   const float* __restrict__ gn1_s, const float* __restrict__ gn1_b,
                                                   const float* __restrict__ se_w2,
                                                   const float* __restrict__ gn2_s, const float* __restrict__ gn2_b,
                                                   float* __restrict__ att_out,
                                                   ushort* __restrict__ aggw) {
    __shared__ float pl[8][128];
    __shared__ float h1s[8][8];
    __shared__ float att_s[8][4];
    int blk = blockIdx.x;
    int rep = blk / 72;
    int t = threadIdx.x;

#pragma unroll
    for (int u = 0; u < 4; ++u) {
        int pid = u * 256 + t;
        int bl = pid >> 7, ic = pid & 127;
        pl[bl][ic] = pooled[(rep * 8 + bl) * 128 + ic];
    }
    __syncthreads();
    if (t < 64) {
        int bl = t >> 3, jj = t & 7;
        float s1 = 0.f;
        for (int c = 0; c < 128; ++c) s1 += pl[bl][c] * se_w1[jj * 128 + c];
        h1s[bl][jj] = s1;
    }
    __syncthreads();
    if (t < 8) {
        float h1[8];
#pragma unroll
        for (int j = 0; j < 8; ++j) h1[j] = h1s[t][j];
        float m = 0.f;
#pragma unroll
        for (int j = 0; j < 8; ++j) m += h1[j];
        m *= 0.125f;
        float var = 0.f;
#pragma unroll
        for (int j = 0; j < 8; ++j) { float d = h1[j] - m; var += d * d; }
        var *= 0.125f;
        float inv = rsqrtf(var + EPS);
#pragma unroll
        for (int j = 0; j < 8; ++j) {
            float tt = (h1[j] - m) * inv * gn1_s[j] + gn1_b[j];
            float sp = (tt > 20.f) ? tt : log1pf(expf(tt));
            h1[j] = tt * tanhf(sp);
        }
        float h2[4];
#pragma unroll
        for (int k = 0; k < 4; ++k) {
            float s2 = 0.f;
#pragma unroll
            for (int j = 0; j < 8; ++j) s2 += h1[j] * se_w2[k * 8 + j];
            h2[k] = s2;
        }
        float m2 = 0.25f * (h2[0] + h2[1] + h2[2] + h2[3]);
        float v2 = 0.f;
#pragma unroll
        for (int k = 0; k < 4; ++k) { float d = h2[k] - m2; v2 += d * d; }
        v2 *= 0.25f;
        float inv2 = rsqrtf(v2 + EPS);
#pragma unroll
        for (int k = 0; k < 4; ++k) {
            float tt = (h2[k] - m2) * inv2 * gn2_s[k] + gn2_b[k];
            att_s[t][k] = 1.0f / (1.0f + expf(-tt));
        }
    }
    __syncthreads();

    if ((blk % 72) == 0 && t < 32) att_out[rep * 32 + t] = att_s[t >> 2][t & 3];

    int tq = (blk % 72) * 256 + t;                     // 0..18431
    int tap = tq >> 10;
    int within = tq & 1023;
    int oc = within >> 3;
    int p = within & 7;
    int g = (p - oc) & 7;
    int h = tap / 9, sp_ = tap % 9;
    int ws = (sp_ % 3) * 3 + sp_ / 3;                  // stored kw-major -> weight tap
    int ic0 = h * 64 + g * 8;

    float wv[4][8];
#pragma unroll
    for (int k = 0; k < 4; ++k)
#pragma unroll
        for (int j = 0; j < 8; ++j)
            wv[k][j] = weight[(((size_t)(k * 128 + oc)) * 128 + ic0 + j) * 9 + ws];

#pragma unroll
    for (int bl = 0; bl < 8; ++bl) {
        int b = rep * 8 + bl;
        float a0 = att_s[bl][0], a1 = att_s[bl][1], a2 = att_s[bl][2], a3 = att_s[bl][3];
        uint pk[4];
#pragma unroll
        for (int q = 0; q < 4; ++q) {
            float f0 = a0 * wv[0][2 * q] + a1 * wv[1][2 * q] + a2 * wv[2][2 * q] + a3 * wv[3][2 * q];
            float f1 = a0 * wv[0][2 * q + 1] + a1 * wv[1][2 * q + 1] + a2 * wv[2][2 * q + 1] + a3 * wv[3][2 * q + 1];
            pk[q] = (uint)f2bf(f0) | ((uint)f2bf(f1) << 16);
        }
        *(uint4*)(aggw + (size_t)b * 147456 + (size_t)tq * 8) = make_uint4(pk[0], pk[1], pk[2], pk[3]);
    }
}

// ---------------------------------------------------------------------------
// Kernel 3: implicit-GEMM conv, mfma_f32_32x32x16_bf16, KH-FUSED B reads.
// grid 512 = 32 b * 16 tiles (4 rows); block 256 = 4 waves (wm: oc-64, wn: row-pair).
// Wave = 64 oc x 128 px, acc[2][4].  Per (h, kw, icb) group: 8 ds_read_b128
// (rows 0..3 x 2 col-halves) -> 24 MFMA (kh=0,1,2 over overlapping row pairs).
// A: depth-1 group prefetch ring aR[2][3][2].  3 barriers total (r5 structure).
// ---------------------------------------------------------------------------
__global__ __launch_bounds__(256, 2) void conv_kernel(const ushort* __restrict__ xT,
                                                      const ushort* __restrict__ aggw,
                                                      const float* __restrict__ att,
                                                      const float* __restrict__ bias,
                                                      float* __restrict__ out) {
    __shared__ ushort ldsB[396 * 64];                 // 6 rows x 66 cols x 8 slots x 16B

    int bid = blockIdx.x;
    int xcd = bid & 7;
    int idx = bid >> 3;                                // 0..63
    int b = xcd * 4 + (idx >> 4);
    int tile = idx & 15;
    int y0 = tile * 4;

    int tid = threadIdx.x;
    int l = tid & 63, w = tid >> 6;
    int wm = w >> 1, wn = w & 1;
    int l31 = l & 31, lhi = l >> 5;

    const ushort* xTb = xT + ((size_t)(b * 66 + y0)) * 66 * 128;  // halo rows y0..y0+5
    const ushort* Asmp = aggw + (size_t)b * 147456;

    int ocofs[2], rotA[2];
#pragma unroll
    for (int mi = 0; mi < 2; ++mi) {
        int oc = wm * 64 + mi * 32 + l31;
        ocofs[mi] = oc * 64;
        rotA[mi] = (lhi + oc) & 7;
    }

    f32x16 acc[2][4];
#pragma unroll
    for (int mi = 0; mi < 2; ++mi)
#pragma unroll
        for (int nb = 0; nb < 4; ++nb)
#pragma unroll
            for (int q = 0; q < 16; ++q) acc[mi][nb][q] = 0.f;

    bf16x8 aR[2][3][2];                                // [ring][kh][mi]

    // load A for (H, KW, ICB): 3 kh taps x 2 mi.  stored tap = H*9 + KW*3 + kh
#define LOADA(P, H, KW, ICB)                                                                 \
    {                                                                                        \
        const ushort* tb_ = Asmp + (size_t)((H) * 9 + (KW) * 3) * 8192;                      \
        _Pragma("unroll")                                                                    \
        for (int kh_ = 0; kh_ < 3; ++kh_)                                                    \
            _Pragma("unroll")                                                                \
            for (int mi_ = 0; mi_ < 2; ++mi_)                                                \
                aR[P][kh_][mi_] = *(const bf16x8*)(tb_ + kh_ * 8192 + ocofs[mi_] +           \
                    (((rotA[mi_] + 2 * (ICB)) & 7) << 3));                                   \
    }

    // stage ic-half H: 3168 chunks of 16B, rotation slots (r5)
#define STAGE(H)                                                                             \
    {                                                                                        \
        _Pragma("unroll")                                                                    \
        for (int i_ = 0; i_ < 13; ++i_) {                                                    \
            int k_ = i_ * 256 + tid;                                                         \
            if (k_ < 3168) {                                                                 \
                int rc_ = k_ >> 3;                                                           \
                int c_ = rc_ % 66;                                                           \
                int g_ = ((k_ & 7) - c_) & 7;                                                \
                dma16(xTb + (size_t)rc_ * 128 + (H) * 64 + (g_ << 3),                        \
                      &ldsB[(size_t)k_ * 8]);                                                \
            }                                                                                \
        }                                                                                    \
    }

    // one group: B reads (4 rows x 2 cols) + 24 MFMA, using ring slot CUR
#define GROUP(CUR, KW, ICB)                                                                  \
    {                                                                                        \
        int c0_ = l31 + (KW);                                                                \
        int c1_ = 32 + l31 + (KW);                                                           \
        int s0_ = (2 * (ICB) + lhi + c0_) & 7;                                               \
        int s1_ = (2 * (ICB) + lhi + c1_) & 7;                                               \
        bf16x8 B_[4][2];                                                                     \
        _Pragma("unroll")                                                                    \
        for (int rr_ = 0; rr_ < 4; ++rr_) {                                                  \
            int cell0_ = (2 * wn + rr_) * 66 + c0_;                                          \
            int cell1_ = (2 * wn + rr_) * 66 + c1_;                                          \
            B_[rr_][0] = *(const bf16x8*)&ldsB[(cell0_ << 6) + (s0_ << 3)];                  \
            B_[rr_][1] = *(const bf16x8*)&ldsB[(cell1_ << 6) + (s1_ << 3)];                  \
        }                                                                                    \
        _Pragma("unroll")                                                                    \
        for (int kh_ = 0; kh_ < 3; ++kh_)                                                    \
            _Pragma("unroll")                                                                \
            for (int mi_ = 0; mi_ < 2; ++mi_)                                                \
                _Pragma("unroll")                                                            \
                for (int rp_ = 0; rp_ < 2; ++rp_)                                            \
                    _Pragma("unroll")                                                        \
                    for (int ch_ = 0; ch_ < 2; ++ch_)                                        \
                        acc[mi_][rp_ * 2 + ch_] = __builtin_amdgcn_mfma_f32_32x32x16_bf16(   \
                            aR[CUR][kh_][mi_], B_[kh_ + rp_][ch_], acc[mi_][rp_ * 2 + ch_],  \
                            0, 0, 0);                                                        \
    }

    // ---- prologue ----
    STAGE(0);
    LOADA(0, 0, 0, 0);
    __syncthreads();

    // ---- h = 0 ----
#pragma unroll
    for (int kw = 0; kw < 3; ++kw) {
#pragma unroll
        for (int icb = 0; icb < 4; ++icb) {
            const int cur = icb & 1;
            // prefetch next group's A (depth-1)
            if (icb < 3)      { LOADA(cur ^ 1, 0, kw, icb + 1); }
            else if (kw < 2)  { LOADA(cur ^ 1, 0, kw + 1, 0); }
            else              { LOADA(cur ^ 1, 1, 0, 0); }
            GROUP(cur, kw, icb);
        }
    }

    __syncthreads();
    STAGE(1);
    __syncthreads();

    // ---- h = 1 ----
#pragma unroll
    for (int kw = 0; kw < 3; ++kw) {
#pragma unroll
        for (int icb = 0; icb < 4; ++icb) {
            const int cur = icb & 1;
            if (icb < 3)      { LOADA(cur ^ 1, 1, kw, icb + 1); }
            else if (kw < 2)  { LOADA(cur ^ 1, 1, kw + 1, 0); }
            GROUP(cur, kw, icb);
        }
    }

    // ---- epilogue: + att@bias, store ----
    float a0 = att[b * 4 + 0], a1 = att[b * 4 + 1], a2 = att[b * 4 + 2], a3 = att[b * 4 + 3];
#pragma unroll
    for (int mi = 0; mi < 2; ++mi)
#pragma unroll
        for (int q = 0; q < 16; ++q) {
            int oc = wm * 64 + mi * 32 + (q & 3) + 8 * (q >> 2) + 4 * lhi;
            float ab = a0 * bias[oc] + a1 * bias[128 + oc] + a2 * bias[256 + oc] + a3 * bias[384 + oc];
#pragma unroll
            for (int nb = 0; nb < 4; ++nb) {
                int y = y0 + 2 * wn + (nb >> 1);
                out[(((size_t)b * 128 + oc) * 64 + y) * 64 + (nb & 1) * 32 + l31] = acc[mi][nb][q] + ab;
            }
        }
#undef LOADA
#undef STAGE
#undef GROUP
}

// ---------------------------------------------------------------------------
extern "C" void kernel_launch(void* const* d_in, const int* in_sizes, int n_in,
                              void* d_out, int out_size, void* d_ws, size_t ws_size,
                              hipStream_t stream) {
    const float* x      = (const float*)d_in[0];
    const float* weight = (const float*)d_in[1];
    const float* bias   = (const float*)d_in[2];
    const float* se_w1  = (const float*)d_in[3];
    const float* gn1_s  = (const float*)d_in[4];
    const float* gn1_b  = (const float*)d_in[5];
    const float* se_w2  = (const float*)d_in[6];
    const float* gn2_s  = (const float*)d_in[7];
    const float* gn2_b  = (const float*)d_in[8];
    float* out = (float*)d_out;

    float*  att    = (float*)d_ws;                              // 512 B
    float*  pooled = (float*)((char*)d_ws + 16384);             // 16 KB
    ushort* aggw   = (ushort*)((char*)d_ws + 65536);            // 9.44 MB
    ushort* xT     = (ushort*)((char*)d_ws + 10485760);         // 35.7 MB

    hipMemsetAsync(pooled, 0, 128 * 32 * sizeof(float), stream);
    transpose_kernel<<<2048, 256, 0, stream>>>(x, xT, pooled);
    aggw_kernel<<<288, 256, 0, stream>>>(weight, pooled, se_w1, gn1_s, gn1_b,
                                         se_w2, gn2_s, gn2_b, att, aggw);
    conv_kernel<<<512, 256, 0, stream>>>(xT, aggw, att, bias, out);
}